// Round 1
// baseline (1339.418 us; speedup 1.0000x reference)
//
#include <hip/hip_runtime.h>
#include <math.h>

// Problem constants
#define BB   4
#define C_   128
#define H_   96
#define W_   192
#define COUT 128
#define DG_  2
#define CG_  64
#define K_   9
#define HO   96
#define WO   192
#define HW   (H_ * W_)      // 18432 (== HO*WO)
#define OMCH 54             // DG*3*K
#define RDIM (C_ * K_)      // 1152

// ---------------------------------------------------------------------------
// Kernel A: grouped offset conv (stride 1, pad 2, dil 2, groups=2)
// One thread computes all 27 output channels of ONE group for ONE pixel.
// idx = g * (B*HO*WO) + pixel  -> g is wave-uniform, pixel coalesced over wo.
// ---------------------------------------------------------------------------
__global__ __launch_bounds__(256) void offset_conv_k(
    const float* __restrict__ x, const float* __restrict__ w_offset,
    const float* __restrict__ b_offset, float* __restrict__ om) {
  int idx = blockIdx.x * 256 + threadIdx.x;       // [0, 2*BB*HO*WO)
  int g   = idx / (BB * HO * WO);
  int pix = idx - g * (BB * HO * WO);
  int b   = pix / (HO * WO);
  int rem = pix - b * (HO * WO);
  int ho  = rem / WO;
  int wo  = rem - ho * WO;

  float acc[27];
#pragma unroll
  for (int j = 0; j < 27; ++j) acc[j] = b_offset[g * 27 + j];

  const float* xg = x + ((size_t)b * C_ + g * CG_) * HW;
  const float* wg = w_offset + (size_t)g * 27 * CG_ * K_;
  int hb = ho - 2, wb = wo - 2;

  for (int ic = 0; ic < CG_; ++ic) {
    const float* xp = xg + (size_t)ic * HW;
    float xv[9];
#pragma unroll
    for (int t = 0; t < 9; ++t) {
      int hy = hb + (t / 3) * 2;
      int wx = wb + (t % 3) * 2;
      bool ok = (hy >= 0) && (hy < H_) && (wx >= 0) && (wx < W_);
      xv[t] = ok ? xp[hy * W_ + wx] : 0.f;
    }
    const float* wp = wg + ic * K_;   // w_offset[((g*27+j)*64+ic)*9 + t]
#pragma unroll
    for (int j = 0; j < 27; ++j) {
      const float* wj = wp + j * CG_ * K_;
      float a = acc[j];
#pragma unroll
      for (int t = 0; t < 9; ++t) a = fmaf(xv[t], wj[t], a);
      acc[j] = a;
    }
  }

  size_t obase = ((size_t)(b * OMCH + g * 27) * HO + ho) * WO + wo;
#pragma unroll
  for (int j = 0; j < 27; ++j) om[obase + (size_t)j * HW] = acc[j];
}

// ---------------------------------------------------------------------------
// Kernel B: fused bilinear sampling + main "einsum" GEMM.
// Block = 64-pixel tile (one ho row segment) x all 128 output channels.
// Phase 0: precompute per (g,k,pixel) the 4 clamped gather addresses and the
//          4 bilinear corner weights (mask folded in, OOB corners zeroed).
// Main loop over r = c*9+k (1152), 4 at a time:
//   - 256 threads compute val[4][64] into LDS (4 gathers + bilinear each)
//   - each thread FMAs 32 output channels x 4 r (weights are wave-uniform).
// ---------------------------------------------------------------------------
__global__ __launch_bounds__(256) void deform_main_k(
    const float* __restrict__ x, const float* __restrict__ om,
    const float* __restrict__ w_deform, float* __restrict__ out) {
  __shared__ int   s_a0[DG_ * K_ * 64], s_a1[DG_ * K_ * 64];
  __shared__ int   s_a2[DG_ * K_ * 64], s_a3[DG_ * K_ * 64];
  __shared__ float s_w0[DG_ * K_ * 64], s_w1[DG_ * K_ * 64];
  __shared__ float s_w2[DG_ * K_ * 64], s_w3[DG_ * K_ * 64];
  __shared__ float s_val[256];

  int blk = blockIdx.x;              // ((b*HO + ho)*3 + wt)
  int wt  = blk % 3;
  int bh  = blk / 3;
  int ho  = bh % HO;
  int b   = bh / HO;
  int wo0 = wt * 64;
  int tid = threadIdx.x;

  // ---- phase 0: bilinear coefficients for all (g,k) x 64 pixels ----
  for (int e = tid; e < DG_ * K_ * 64; e += 256) {
    int p  = e & 63;
    int gk = e >> 6;                 // g*9 + k
    int g  = gk / 9, k = gk - g * 9;
    int wo = wo0 + p;
    const float* omb = om + (size_t)b * OMCH * HW + (size_t)ho * WO + wo;
    float offy = omb[(size_t)(g * 18 + k * 2 + 0) * HW];
    float offx = omb[(size_t)(g * 18 + k * 2 + 1) * HW];
    float z    = omb[(size_t)(36 + g * 9 + k) * HW];
    float m  = 2.f / (1.f + expf(-z));
    float py = (float)(ho - 2 + (k / 3) * 2) + offy;
    float px = (float)(wo - 2 + (k % 3) * 2) + offx;
    float y0f = floorf(py), x0f = floorf(px);
    int   y0  = (int)y0f,  x0  = (int)x0f;
    float ty = py - y0f, tx = px - x0f;
    float wy0 = (y0 >= 0  && y0 < H_)      ? (1.f - ty) : 0.f;
    float wy1 = (y0 >= -1 && y0 < H_ - 1)  ? ty         : 0.f;
    float wx0 = (x0 >= 0  && x0 < W_)      ? (1.f - tx) : 0.f;
    float wx1 = (x0 >= -1 && x0 < W_ - 1)  ? tx         : 0.f;
    int y0c = min(max(y0, 0), H_ - 1), y1c = min(max(y0 + 1, 0), H_ - 1);
    int x0c = min(max(x0, 0), W_ - 1), x1c = min(max(x0 + 1, 0), W_ - 1);
    s_a0[e] = y0c * W_ + x0c;  s_a1[e] = y0c * W_ + x1c;
    s_a2[e] = y1c * W_ + x0c;  s_a3[e] = y1c * W_ + x1c;
    s_w0[e] = wy0 * wx0 * m;   s_w1[e] = wy0 * wx1 * m;
    s_w2[e] = wy1 * wx0 * m;   s_w3[e] = wy1 * wx1 * m;
  }
  __syncthreads();

  int p   = tid & 63;
  int ocg = __builtin_amdgcn_readfirstlane(tid >> 6);   // wave-uniform 0..3
  float acc[32];
#pragma unroll
  for (int j = 0; j < 32; ++j) acc[j] = 0.f;
  const float* xb = x + (size_t)b * C_ * HW;

  for (int rb = 0; rb < RDIM; rb += 4) {
    int r = rb + ocg;                // scalar
    int c = r / 9, k = r - c * 9;
    int g = c >> 6;
    int e = (g * 9 + k) * 64 + p;
    const float* plane = xb + (size_t)c * HW;
    float v = s_w0[e] * plane[s_a0[e]] + s_w1[e] * plane[s_a1[e]]
            + s_w2[e] * plane[s_a2[e]] + s_w3[e] * plane[s_a3[e]];
    __syncthreads();                 // previous batch fully consumed
    s_val[tid] = v;
    __syncthreads();                 // val visible to all

    const float* wrow = w_deform + (size_t)(ocg * 32) * RDIM + rb;
    float v0 = s_val[p], v1 = s_val[64 + p], v2 = s_val[128 + p], v3 = s_val[192 + p];
#pragma unroll
    for (int j = 0; j < 32; ++j) {
      float4 wv = *(const float4*)(wrow + (size_t)j * RDIM);
      acc[j] = fmaf(wv.x, v0, acc[j]);
      acc[j] = fmaf(wv.y, v1, acc[j]);
      acc[j] = fmaf(wv.z, v2, acc[j]);
      acc[j] = fmaf(wv.w, v3, acc[j]);
    }
  }

  size_t obase = ((size_t)(b * COUT + ocg * 32) * HO + ho) * WO + wo0 + p;
#pragma unroll
  for (int j = 0; j < 32; ++j) out[obase + (size_t)j * HW] = acc[j];
}

// ---------------------------------------------------------------------------
extern "C" void kernel_launch(void* const* d_in, const int* in_sizes, int n_in,
                              void* d_out, int out_size, void* d_ws, size_t ws_size,
                              hipStream_t stream) {
  const float* x        = (const float*)d_in[0];
  const float* w_offset = (const float*)d_in[1];
  const float* b_offset = (const float*)d_in[2];
  const float* w_deform = (const float*)d_in[3];
  float* out = (float*)d_out;
  float* om  = (float*)d_ws;   // 4*54*96*192*4 B = 15.2 MiB scratch

  // Kernel A: 2 groups * 4*96*192 pixels = 147456 threads
  offset_conv_k<<<576, 256, 0, stream>>>(x, w_offset, b_offset, om);
  // Kernel B: 4*96*3 = 1152 blocks of 256 threads
  deform_main_k<<<1152, 256, 0, stream>>>(x, om, w_deform, out);
}

// Round 2
// 542.412 us; speedup vs baseline: 2.4694x; 2.4694x over previous
//
#include <hip/hip_runtime.h>
#include <hip/hip_fp16.h>
#include <math.h>

#define BB   4
#define C_   128
#define H_   96
#define W_   192
#define COUT 128
#define DG_  2
#define CG_  64
#define K_   9
#define HO   96
#define WO   192
#define HW   (H_ * W_)       // 18432
#define OMCH 54
#define RDIM (C_ * K_)       // 1152
#define NKS  (RDIM / 32)     // 36 K-steps

typedef __attribute__((ext_vector_type(8))) short bf16x8;
typedef __attribute__((ext_vector_type(4))) float f32x4;

static __device__ __forceinline__ ushort f2bf(float f) {
  union { float f; uint u; } v; v.f = f;
  uint r = v.u + 0x7fff + ((v.u >> 16) & 1);   // RNE
  return (ushort)(r >> 16);
}

// ---------------------------------------------------------------------------
// Kernel A: grouped offset conv. Block = (b,ho,64-px tile,g); wave w handles
// 16 input channels; LDS reduce of 4 partials. 2304 blocks -> 36 waves/CU.
// ---------------------------------------------------------------------------
__global__ __launch_bounds__(256) void offset_conv_k(
    const float* __restrict__ x, const float* __restrict__ w_offset,
    const float* __restrict__ b_offset, float* __restrict__ om) {
  __shared__ float s_part[4][27][64];

  int bid = blockIdx.x;
  int swz = (bid & 7) * 288 + (bid >> 3);       // bijective, 2304 % 8 == 0
  int g   = swz / 1152;
  int r0  = swz - g * 1152;                     // (b*HO + ho)*3 + wt
  int wt  = r0 % 3;
  int bh  = r0 / 3;
  int ho  = bh % HO;
  int b   = bh / HO;
  int lane = threadIdx.x & 63;
  int wv   = threadIdx.x >> 6;
  int wo   = wt * 64 + lane;

  const float* xg = x + ((size_t)b * C_ + g * CG_ + wv * 16) * HW;
  const float* wg = w_offset + (size_t)g * 27 * CG_ * K_ + (size_t)(wv * 16) * K_;
  int hb = ho - 2, wb = wo - 2;

  float acc[27];
#pragma unroll
  for (int j = 0; j < 27; ++j) acc[j] = 0.f;

  for (int ic = 0; ic < 16; ++ic) {
    const float* xp = xg + (size_t)ic * HW;
    float xv[9];
#pragma unroll
    for (int t = 0; t < 9; ++t) {
      int hy = hb + (t / 3) * 2;
      int wx = wb + (t % 3) * 2;
      bool ok = (hy >= 0) && (hy < H_) && (wx >= 0) && (wx < W_);
      xv[t] = ok ? xp[hy * W_ + wx] : 0.f;
    }
    const float* wp = wg + ic * K_;
#pragma unroll
    for (int j = 0; j < 27; ++j) {
      const float* wj = wp + j * CG_ * K_;
      float a = acc[j];
#pragma unroll
      for (int t = 0; t < 9; ++t) a = fmaf(xv[t], wj[t], a);
      acc[j] = a;
    }
  }

#pragma unroll
  for (int j = 0; j < 27; ++j) s_part[wv][j][lane] = acc[j];
  __syncthreads();

  for (int e = threadIdx.x; e < 27 * 64; e += 256) {
    int j = e >> 6, p = e & 63;
    float sum = s_part[0][j][p] + s_part[1][j][p] + s_part[2][j][p] +
                s_part[3][j][p] + b_offset[g * 27 + j];
    om[((size_t)(b * OMCH + g * 27 + j) * HO + ho) * WO + wt * 64 + p] = sum;
  }
}

// ---------------------------------------------------------------------------
// Kernel B: fused bilinear sampling + bf16 MFMA GEMM.
// Block = 64 px x 128 Cout, 4 waves. K-loop: 36 steps of 32 r, double-buffered
// val in LDS, ONE barrier per step. Wave wv: Cout [wv*32, wv*32+32).
// val producer: thread(p=lane, s=wv) computes r = rb + s*8 + j, j=0..7.
// ---------------------------------------------------------------------------
__global__ __launch_bounds__(256) void deform_main_k(
    const float* __restrict__ x, const float* __restrict__ om,
    const float* __restrict__ w_deform, float* __restrict__ out) {
  __shared__ int4 s_coef[18 * 64];       // 18432 B: {a0, dx|dyW<<16, h2(w0,w1), h2(w2,w3)}
  __shared__ uint s_val[2][64][20];      // 10240 B: [buf][pixel][16 used + 4 pad] bf16x2

  int bid = blockIdx.x;
  int blk = (bid & 7) * 144 + (bid >> 3);      // bijective, 1152 % 8 == 0
  int wt = blk % 3, bh = blk / 3;
  int ho = bh % HO, b = bh / HO;
  int wo0 = wt * 64;
  int tid = threadIdx.x;
  int lane = tid & 63, wv = tid >> 6;

  // ---- phase 0: bilinear coefficients for 18 (g,k) x 64 pixels ----
  for (int e = tid; e < 18 * 64; e += 256) {
    int p = e & 63, gk = e >> 6;
    int g = gk / 9, k = gk - g * 9;
    int wo = wo0 + p;
    const float* omb = om + (size_t)b * OMCH * HW + (size_t)ho * WO + wo;
    float offy = omb[(size_t)(g * 18 + k * 2 + 0) * HW];
    float offx = omb[(size_t)(g * 18 + k * 2 + 1) * HW];
    float z    = omb[(size_t)(36 + g * 9 + k) * HW];
    float msk  = 2.f / (1.f + __expf(-z));
    float py = (float)(ho - 2 + (k / 3) * 2) + offy;
    float px = (float)(wo - 2 + (k % 3) * 2) + offx;
    float y0f = floorf(py), x0f = floorf(px);
    int   y0 = (int)y0f, x0 = (int)x0f;
    float ty = py - y0f, tx = px - x0f;
    float wy0 = (y0 >= 0 && y0 < H_)       ? (1.f - ty) : 0.f;
    float wy1 = (y0 >= -1 && y0 < H_ - 1)  ? ty         : 0.f;
    float wx0 = (x0 >= 0 && x0 < W_)       ? (1.f - tx) : 0.f;
    float wx1 = (x0 >= -1 && x0 < W_ - 1)  ? tx         : 0.f;
    int y0c = min(max(y0, 0), H_ - 1), y1c = min(max(y0 + 1, 0), H_ - 1);
    int x0c = min(max(x0, 0), W_ - 1), x1c = min(max(x0 + 1, 0), W_ - 1);
    int4 cf;
    cf.x = y0c * W_ + x0c;
    cf.y = (x1c - x0c) | (((y1c - y0c) * W_) << 16);
    union { __half2 h; int i; } u01, u23;
    u01.h = __half2{__float2half(wy0 * wx0 * msk), __float2half(wy0 * wx1 * msk)};
    u23.h = __half2{__float2half(wy1 * wx0 * msk), __float2half(wy1 * wx1 * msk)};
    cf.z = u01.i; cf.w = u23.i;
    s_coef[e] = cf;
  }

  const float* xb = x + (size_t)b * C_ * HW;
  int p = lane, s = wv;

  f32x4 acc[2][4];
#pragma unroll
  for (int m = 0; m < 2; ++m)
#pragma unroll
    for (int n = 0; n < 4; ++n) acc[m][n] = (f32x4){0.f, 0.f, 0.f, 0.f};

  // A-operand base pointers (fp32 W, converted on the fly; L2-resident)
  const float* wbase0 = w_deform + (size_t)(wv * 32 + (lane & 15)) * RDIM + (lane >> 4) * 8;
  const float* wbase1 = wbase0 + (size_t)16 * RDIM;

  float ga0[8], ga1[8], ga2[8], ga3[8];
  uint  wp01[8], wp23[8];

  auto val_gather = [&](int step) {
    int r0 = step * 32 + s * 8;
    int c = (r0 * 7282) >> 16;           // c = r0 / 9 (magic, valid r0 < 3276)
    int k = r0 - c * 9;
    const float* plane = xb + (size_t)c * HW;
#pragma unroll
    for (int j = 0; j < 8; ++j) {
      int gk = (c >> 6) * 9 + k;
      int4 cf = s_coef[gk * 64 + p];
      int a0 = cf.x;
      int dx = cf.y & 0xffff, dyw = cf.y >> 16;
      ga0[j] = plane[a0];
      ga1[j] = plane[a0 + dx];
      ga2[j] = plane[a0 + dyw];
      ga3[j] = plane[a0 + dyw + dx];
      wp01[j] = (uint)cf.z; wp23[j] = (uint)cf.w;
      ++k;
      if (k == 9) { k = 0; ++c; plane += HW; }
    }
  };

  auto val_finish = [&](int nb) {
    uint res[4];
#pragma unroll
    for (int j = 0; j < 8; ++j) {
      union { __half2 h; uint u; } a, bu;
      a.u = wp01[j]; bu.u = wp23[j];
      float2 w01 = __half22float2(a.h);
      float2 w23 = __half22float2(bu.h);
      float v = w01.x * ga0[j] + w01.y * ga1[j] + w23.x * ga2[j] + w23.y * ga3[j];
      uint bf = (uint)f2bf(v);
      if (j & 1) res[j >> 1] |= bf << 16; else res[j >> 1] = bf;
    }
    *(int4*)&s_val[nb][p][s * 4] = *(int4*)&res[0];
  };

  auto mfma_step = [&](int step, int cb) {
    int rb = step * 32;
    bf16x8 afr[2];
#pragma unroll
    for (int m = 0; m < 2; ++m) {
      const float* wr = (m ? wbase1 : wbase0) + rb;
      f32x4 lo = *(const f32x4*)wr;
      f32x4 hi = *(const f32x4*)(wr + 4);
      union { bf16x8 v; ushort u[8]; } t;
#pragma unroll
      for (int q = 0; q < 4; ++q) { t.u[q] = f2bf(lo[q]); t.u[4 + q] = f2bf(hi[q]); }
      afr[m] = t.v;
    }
#pragma unroll
    for (int n = 0; n < 4; ++n) {
      bf16x8 bfr = *(const bf16x8*)&s_val[cb][n * 16 + (lane & 15)][(lane >> 4) * 4];
      acc[0][n] = __builtin_amdgcn_mfma_f32_16x16x32_bf16(afr[0], bfr, acc[0][n], 0, 0, 0);
      acc[1][n] = __builtin_amdgcn_mfma_f32_16x16x32_bf16(afr[1], bfr, acc[1][n], 0, 0, 0);
    }
  };

  __syncthreads();                 // coeffs ready
  val_gather(0);
  val_finish(0);
  __syncthreads();                 // buf0 ready

  for (int it = 0; it < NKS - 1; ++it) {
    val_gather(it + 1);            // issue gathers early
    mfma_step(it, it & 1);         // MFMA overlaps gather latency
    val_finish((it + 1) & 1);      // combine + write next buffer
    __syncthreads();
  }
  mfma_step(NKS - 1, (NKS - 1) & 1);

  // ---- epilogue: C/D layout col=lane&15, row=(lane>>4)*4+reg ----
  int col = lane & 15, rgrp = lane >> 4;
#pragma unroll
  for (int m = 0; m < 2; ++m)
#pragma unroll
    for (int n = 0; n < 4; ++n)
#pragma unroll
      for (int ri = 0; ri < 4; ++ri) {
        int o = wv * 32 + m * 16 + rgrp * 4 + ri;
        out[((size_t)(b * COUT + o) * HO + ho) * WO + wo0 + n * 16 + col] = acc[m][n][ri];
      }
}

// ---------------------------------------------------------------------------
extern "C" void kernel_launch(void* const* d_in, const int* in_sizes, int n_in,
                              void* d_out, int out_size, void* d_ws, size_t ws_size,
                              hipStream_t stream) {
  const float* x        = (const float*)d_in[0];
  const float* w_offset = (const float*)d_in[1];
  const float* b_offset = (const float*)d_in[2];
  const float* w_deform = (const float*)d_in[3];
  float* out = (float*)d_out;
  float* om  = (float*)d_ws;                     // 15.2 MiB scratch

  offset_conv_k<<<2304, 256, 0, stream>>>(x, w_offset, b_offset, om);
  deform_main_k<<<1152, 256, 0, stream>>>(x, om, w_deform, out);
}

// Round 3
// 285.416 us; speedup vs baseline: 4.6929x; 1.9004x over previous
//
#include <hip/hip_runtime.h>
#include <hip/hip_fp16.h>
#include <math.h>

#define BB   4
#define C_   128
#define H_   96
#define W_   192
#define COUT 128
#define DG_  2
#define CG_  64
#define K_   9
#define HO   96
#define WO   192
#define HW   (H_ * W_)       // 18432
#define OMCH 54
#define RDIM (C_ * K_)       // 1152
#define NKS  (RDIM / 32)     // 36 K-steps

typedef __attribute__((ext_vector_type(8))) short bf16x8;
typedef __attribute__((ext_vector_type(4))) float f32x4;

static __device__ __forceinline__ ushort f2bf(float f) {
  union { float f; uint u; } v; v.f = f;
  uint r = v.u + 0x7fff + ((v.u >> 16) & 1);   // RNE
  return (ushort)(r >> 16);
}

// ---------------------------------------------------------------------------
// Prep: convert weights to bf16 in the k-major r-orderings used below.
//  Wt [128][1152]  r' = g*576 + k*64 + cg   (main GEMM A)
//  Awo[ 64][1152]  r''= k*128 + c, rows o'=g*32+j (j<27 real, else 0) (offset A)
// ---------------------------------------------------------------------------
__global__ __launch_bounds__(256) void prep_k(
    const float* __restrict__ wd, const float* __restrict__ wo,
    ushort* __restrict__ Wt, ushort* __restrict__ Awo) {
  int i = blockIdx.x * 256 + threadIdx.x;
  if (i < 128 * RDIM) {
    int o = i / RDIM, r = i - o * RDIM;
    int g = r / 576, t = r - g * 576;
    int k = t >> 6, cg = t & 63;
    Wt[i] = f2bf(wd[((size_t)o * C_ + g * 64 + cg) * 9 + k]);
  }
  if (i < 64 * RDIM) {
    int o2 = i / RDIM, r = i - o2 * RDIM;
    int k = r >> 7, c = r & 127;
    int g = o2 >> 5, j = o2 & 31;
    float v = (((c >> 6) == g) && (j < 27))
                ? wo[(((size_t)(g * 27 + j)) * 64 + (c & 63)) * 9 + k] : 0.f;
    Awo[i] = f2bf(v);
  }
}

// ---------------------------------------------------------------------------
// Offset conv as MFMA: om[o'][p] = sum_r Awo[o'][r] * patch[r][p].
// Block = (b,ho,64px), 4 waves; wave wv = M-tile wv (rows 16wv..16wv+15).
// patch producer: thread (p=lane, s=wv) -> r = step*32 + s*8 + j, coalesced
// loads (fixed k per step, 8 channel planes). Double-buffered LDS val.
// ---------------------------------------------------------------------------
__global__ __launch_bounds__(256) void offset_mfma_k(
    const float* __restrict__ x, const ushort* __restrict__ Awo,
    const float* __restrict__ b_offset, float* __restrict__ om) {
  __shared__ uint s_val[2][64][20];

  int bid = blockIdx.x;
  int blk = (bid & 7) * 144 + (bid >> 3);
  int wt = blk % 3, bh = blk / 3;
  int ho = bh % HO, b = bh / HO;
  int wo0 = wt * 64;
  int lane = threadIdx.x & 63, wv = threadIdx.x >> 6;

  const float* xb = x + (size_t)b * C_ * HW;
  f32x4 acc[4];
#pragma unroll
  for (int n = 0; n < 4; ++n) acc[n] = (f32x4){0.f, 0.f, 0.f, 0.f};

  const ushort* abase = Awo + (size_t)(wv * 16 + (lane & 15)) * RDIM + (lane >> 4) * 8;

  float gv[8];

  auto patch_gather = [&](int step) {
    int k = step >> 2;               // 0..8
    int dy = k / 3, dx = k - dy * 3;
    int y  = ho - 2 + 2 * dy;
    int xc = wo0 + lane - 2 + 2 * dx;
    bool ok = (y >= 0) & (y < H_) & (xc >= 0) & (xc < W_);
    int c0 = (step & 3) * 32 + wv * 8;
    const float* pl = xb + ((ptrdiff_t)c0 * HW + y * W_ + xc);
#pragma unroll
    for (int j = 0; j < 8; ++j) { gv[j] = ok ? *pl : 0.f; pl += HW; }
  };

  auto patch_finish = [&](int nb) {
    uint res[4];
#pragma unroll
    for (int j = 0; j < 8; ++j) {
      uint bf = (uint)f2bf(gv[j]);
      if (j & 1) res[j >> 1] |= bf << 16; else res[j >> 1] = bf;
    }
    *(int4*)&s_val[nb][lane][wv * 4] = *(int4*)&res[0];
  };

  auto mfma_step = [&](int step, int cb) {
    bf16x8 af = *(const bf16x8*)(abase + step * 32);
#pragma unroll
    for (int n = 0; n < 4; ++n) {
      bf16x8 bfr = *(const bf16x8*)&s_val[cb][n * 16 + (lane & 15)][(lane >> 4) * 4];
      acc[n] = __builtin_amdgcn_mfma_f32_16x16x32_bf16(af, bfr, acc[n], 0, 0, 0);
    }
  };

  patch_gather(0);
  patch_finish(0);
  __syncthreads();
  for (int it = 0; it < NKS - 1; ++it) {
    patch_gather(it + 1);
    mfma_step(it, it & 1);
    patch_finish((it + 1) & 1);
    __syncthreads();
  }
  mfma_step(NKS - 1, (NKS - 1) & 1);

  int col = lane & 15, rgrp = lane >> 4;
#pragma unroll
  for (int n = 0; n < 4; ++n)
#pragma unroll
    for (int ri = 0; ri < 4; ++ri) {
      int o2 = wv * 16 + rgrp * 4 + ri;
      int g = o2 >> 5, j = o2 & 31;
      if (j < 27) {
        int ch = g * 27 + j;
        om[((size_t)(b * OMCH + ch) * HO + ho) * WO + wo0 + n * 16 + col] =
            acc[n][ri] + b_offset[ch];
      }
    }
}

// ---------------------------------------------------------------------------
// Main kernel: bilinear sampling + bf16 MFMA GEMM, k-major reduction order.
// Per step: fixed (g,k) -> 1 coef read, 8 channel planes, 32 gathers.
// ---------------------------------------------------------------------------
__global__ __launch_bounds__(256) void deform_main_k(
    const float* __restrict__ x, const float* __restrict__ om,
    const ushort* __restrict__ Wt, float* __restrict__ out) {
  __shared__ uint  s_addr[18 * 64];        // 4608 B: a0|dx<<15|dy<<16
  __shared__ uint2 s_w[18 * 64];           // 9216 B: 4 x f16 mask-folded weights
  __shared__ uint  s_val[2][64][20];       // 10240 B

  int bid = blockIdx.x;
  int blk = (bid & 7) * 144 + (bid >> 3);
  int wt = blk % 3, bh = blk / 3;
  int ho = bh % HO, b = bh / HO;
  int wo0 = wt * 64;
  int tid = threadIdx.x;
  int lane = tid & 63, wv = tid >> 6;

  // phase 0: coefficients for 18 (g,k) x 64 px
  for (int e = tid; e < 18 * 64; e += 256) {
    int p = e & 63, gk = e >> 6;
    int g = gk / 9, k = gk - g * 9;
    int wo = wo0 + p;
    const float* omb = om + (size_t)b * OMCH * HW + (size_t)ho * WO + wo;
    float offy = omb[(size_t)(g * 18 + k * 2 + 0) * HW];
    float offx = omb[(size_t)(g * 18 + k * 2 + 1) * HW];
    float z    = omb[(size_t)(36 + g * 9 + k) * HW];
    float msk  = 2.f / (1.f + __expf(-z));
    float py = (float)(ho - 2 + (k / 3) * 2) + offy;
    float px = (float)(wo - 2 + (k % 3) * 2) + offx;
    float y0f = floorf(py), x0f = floorf(px);
    int   y0 = (int)y0f, x0 = (int)x0f;
    float ty = py - y0f, tx = px - x0f;
    float wy0 = (y0 >= 0 && y0 < H_)       ? (1.f - ty) : 0.f;
    float wy1 = (y0 >= -1 && y0 < H_ - 1)  ? ty         : 0.f;
    float wx0 = (x0 >= 0 && x0 < W_)       ? (1.f - tx) : 0.f;
    float wx1 = (x0 >= -1 && x0 < W_ - 1)  ? tx         : 0.f;
    int y0c = min(max(y0, 0), H_ - 1), y1c = min(max(y0 + 1, 0), H_ - 1);
    int x0c = min(max(x0, 0), W_ - 1), x1c = min(max(x0 + 1, 0), W_ - 1);
    s_addr[e] = (uint)(y0c * W_ + x0c) | ((uint)(x1c - x0c) << 15)
              | ((uint)(y1c - y0c) << 16);
    union { __half2 h; uint u; } u01, u23;
    u01.h = __half2{__float2half(wy0 * wx0 * msk), __float2half(wy0 * wx1 * msk)};
    u23.h = __half2{__float2half(wy1 * wx0 * msk), __float2half(wy1 * wx1 * msk)};
    s_w[e] = make_uint2(u01.u, u23.u);
  }

  const float* xb = x + (size_t)b * C_ * HW;

  f32x4 acc[2][4];
#pragma unroll
  for (int m = 0; m < 2; ++m)
#pragma unroll
    for (int n = 0; n < 4; ++n) acc[m][n] = (f32x4){0.f, 0.f, 0.f, 0.f};

  const ushort* wbase0 = Wt + (size_t)(wv * 32 + (lane & 15)) * RDIM + (lane >> 4) * 8;
  const ushort* wbase1 = wbase0 + (size_t)16 * RDIM;

  float ga0[8], ga1[8], ga2[8], ga3[8];
  float4 wgt;

  auto val_gather = [&](int step) {
    int g  = step >= 18;
    int ks = step - g * 18;          // 0..17
    int k  = ks >> 1, half = ks & 1;
    int ci = (g * 9 + k) * 64 + lane;
    uint aw  = s_addr[ci];
    uint2 wp = s_w[ci];
    union { __half2 h; uint u; } ua, ub;
    ua.u = wp.x; ub.u = wp.y;
    float2 w01 = __half22float2(ua.h);
    float2 w23 = __half22float2(ub.h);
    wgt = make_float4(w01.x, w01.y, w23.x, w23.y);
    int a0  = (int)(aw & 0x7fffu);
    int dx  = (int)((aw >> 15) & 1u);
    int dyw = (int)((aw >> 16) & 1u) * W_;
    int c0 = g * 64 + half * 32 + wv * 8;
    const float* pl = xb + (size_t)c0 * HW;
#pragma unroll
    for (int j = 0; j < 8; ++j) {
      ga0[j] = pl[a0];
      ga1[j] = pl[a0 + dx];
      ga2[j] = pl[a0 + dyw];
      ga3[j] = pl[a0 + dyw + dx];
      pl += HW;
    }
  };

  auto val_finish = [&](int nb) {
    uint res[4];
#pragma unroll
    for (int j = 0; j < 8; ++j) {
      float v = wgt.x * ga0[j] + wgt.y * ga1[j] + wgt.z * ga2[j] + wgt.w * ga3[j];
      uint bf = (uint)f2bf(v);
      if (j & 1) res[j >> 1] |= bf << 16; else res[j >> 1] = bf;
    }
    *(int4*)&s_val[nb][lane][wv * 4] = *(int4*)&res[0];
  };

  auto mfma_step = [&](int step, int cb) {
    bf16x8 a0f = *(const bf16x8*)(wbase0 + step * 32);
    bf16x8 a1f = *(const bf16x8*)(wbase1 + step * 32);
#pragma unroll
    for (int n = 0; n < 4; ++n) {
      bf16x8 bfr = *(const bf16x8*)&s_val[cb][n * 16 + (lane & 15)][(lane >> 4) * 4];
      acc[0][n] = __builtin_amdgcn_mfma_f32_16x16x32_bf16(a0f, bfr, acc[0][n], 0, 0, 0);
      acc[1][n] = __builtin_amdgcn_mfma_f32_16x16x32_bf16(a1f, bfr, acc[1][n], 0, 0, 0);
    }
  };

  __syncthreads();                 // coeffs ready
  val_gather(0);
  val_finish(0);
  __syncthreads();
  for (int it = 0; it < NKS - 1; ++it) {
    val_gather(it + 1);
    mfma_step(it, it & 1);
    val_finish((it + 1) & 1);
    __syncthreads();
  }
  mfma_step(NKS - 1, (NKS - 1) & 1);

  int col = lane & 15, rgrp = lane >> 4;
#pragma unroll
  for (int m = 0; m < 2; ++m)
#pragma unroll
    for (int n = 0; n < 4; ++n)
#pragma unroll
      for (int ri = 0; ri < 4; ++ri) {
        int o = wv * 32 + m * 16 + rgrp * 4 + ri;
        out[((size_t)(b * COUT + o) * HO + ho) * WO + wo0 + n * 16 + col] = acc[m][n][ri];
      }
}

// ---------------------------------------------------------------------------
extern "C" void kernel_launch(void* const* d_in, const int* in_sizes, int n_in,
                              void* d_out, int out_size, void* d_ws, size_t ws_size,
                              hipStream_t stream) {
  const float* x        = (const float*)d_in[0];
  const float* w_offset = (const float*)d_in[1];
  const float* b_offset = (const float*)d_in[2];
  const float* w_deform = (const float*)d_in[3];
  float* out = (float*)d_out;

  char* ws = (char*)d_ws;
  float*  om  = (float*)ws;                           // 15,925,248 B
  ushort* Wt  = (ushort*)(ws + 15925248);             //    294,912 B
  ushort* Awo = (ushort*)(ws + 15925248 + 294912);    //    147,456 B

  prep_k<<<576, 256, 0, stream>>>(w_deform, w_offset, Wt, Awo);
  offset_mfma_k<<<1152, 256, 0, stream>>>(x, Awo, b_offset, om);
  deform_main_k<<<1152, 256, 0, stream>>>(x, om, Wt, out);
}